// Round 9
// baseline (67.676 us; speedup 1.0000x reference)
//
#include <hip/hip_runtime.h>

// RQCNN quanvolution: B=32, C=3, H=W=128, K=2 -> R=127, 4 qubits, 4 layers.
// Output [B,4,R,R] is a flat reinterpretation of q_out [B,R,R,4].
//
// R9 = R8 with the compile fix: h2 must be __fp16-based (that's what
// __builtin_amdgcn_cvt_pkrtz returns); _Float16 vectors don't implicitly
// convert. Body in packed f16 (v_pk_fma_f16, true 2x vs f32); trans, angle
// math, cross-channel accumulation and S^2 fold stay f32.

#define BATCH   32
#define CHAN    3
#define HDIM    128
#define WDIM    128
#define RDIM    127
#define HALFB   16

typedef float v2f __attribute__((ext_vector_type(2)));
typedef __fp16 h2 __attribute__((ext_vector_type(2)));

__global__ __launch_bounds__(256) void rqcnn_kernel(
    const float* __restrict__ x,   // [B,C,H,W]
    const float* __restrict__ w,   // [4,4] weights
    float* __restrict__ out)       // [B*R*R*4]
{
    __shared__ float tw_s[12];     // tan(w/2) for layers 1..3
    __shared__ float wrev_s[4];    // layer-0 weights in revolutions (merged into encoding)
    __shared__ float cw_tmp[16];
    __shared__ float sc2_s;        // (prod cos(w/2), layers 1..3)^2
    const int t = threadIdx.x;
    if (t < 16) {
        float rev = w[t] * 0.07957747154594767f;   // w/(4*pi): half-angle in revolutions
        float c = __builtin_amdgcn_cosf(rev);
        float s = __builtin_amdgcn_sinf(rev);
        cw_tmp[t] = c;
        if (t >= 4) tw_s[t - 4] = s / c;
        else        wrev_s[t]   = rev;
    }
    __syncthreads();
    if (t == 0) {
        float P = 1.f;
        #pragma unroll
        for (int k = 4; k < 16; ++k) P *= cw_tmp[k];
        sc2_s = P * P;
    }
    __syncthreads();

    // hoist to registers; tan splatted to h2 for packed-f16 FMAs
    h2 tw[12];
    #pragma unroll
    for (int k = 0; k < 12; ++k) {
        __fp16 th = (__fp16)tw_s[k];
        tw[k] = (h2){th, th};
    }
    float wr0 = wrev_s[0], wr1 = wrev_s[1], wr2 = wrev_s[2], wr3 = wrev_s[3];
    float sc2 = sc2_s;

    const int NHALF = HALFB * RDIM * RDIM;     // 258,064 threads, 2 pixels each
    int tid = blockIdx.x * 256 + t;
    if (tid >= NHALF) return;

    int j    = tid % RDIM;
    int rest = tid / RDIM;
    int i    = rest % RDIM;
    int b    = rest / RDIM;                    // 0..15; second pixel is b+16

    const int XOFF = HALFB * CHAN * HDIM * WDIM;   // offset of batch b+16

    v2f z0 = 0.f, z1 = 0.f, z2 = 0.f, z3 = 0.f;

    for (int c = 0; c < CHAN; ++c) {
        int base = ((b * CHAN + c) * HDIM + i) * WDIM + j;
        v2f v0, v1, v2v, v3;
        v0.x  = x[base];              v0.y  = x[base + XOFF];
        v1.x  = x[base + 1];          v1.y  = x[base + XOFF + 1];
        v2v.x = x[base + WDIM];       v2v.y = x[base + XOFF + WDIM];
        v3.x  = x[base + WDIM + 1];   v3.y  = x[base + XOFF + WDIM + 1];

        // merged encoding + layer-0 RY: half-angle (pi*v + w0q)/2 in revolutions
        v2f a0 = 0.25f * v0 + wr0;
        v2f a1 = 0.25f * v1 + wr1;
        v2f a2 = 0.25f * v2v + wr2;
        v2f a3 = 0.25f * v3 + wr3;

        // f32 trans, packed-cvt to f16 pairs (2 pixels share one h2 reg)
        h2 ca0 = __builtin_amdgcn_cvt_pkrtz(__builtin_amdgcn_cosf(a0.x), __builtin_amdgcn_cosf(a0.y));
        h2 sa0 = __builtin_amdgcn_cvt_pkrtz(__builtin_amdgcn_sinf(a0.x), __builtin_amdgcn_sinf(a0.y));
        h2 ca1 = __builtin_amdgcn_cvt_pkrtz(__builtin_amdgcn_cosf(a1.x), __builtin_amdgcn_cosf(a1.y));
        h2 sa1 = __builtin_amdgcn_cvt_pkrtz(__builtin_amdgcn_sinf(a1.x), __builtin_amdgcn_sinf(a1.y));
        h2 ca2 = __builtin_amdgcn_cvt_pkrtz(__builtin_amdgcn_cosf(a2.x), __builtin_amdgcn_cosf(a2.y));
        h2 sa2 = __builtin_amdgcn_cvt_pkrtz(__builtin_amdgcn_sinf(a2.x), __builtin_amdgcn_sinf(a2.y));
        h2 ca3 = __builtin_amdgcn_cvt_pkrtz(__builtin_amdgcn_cosf(a3.x), __builtin_amdgcn_cosf(a3.y));
        h2 sa3 = __builtin_amdgcn_cvt_pkrtz(__builtin_amdgcn_sinf(a3.x), __builtin_amdgcn_sinf(a3.y));

        // qubit q maps to bit (3-q) of flat index s
        h2 aq[2] = {ca0, sa0};
        h2 bq[2] = {ca1, sa1};
        h2 cq[2] = {ca2, sa2};
        h2 dq[2] = {ca3, sa3};

        h2 st[16];
        #pragma unroll
        for (int ia = 0; ia < 2; ++ia) {
            #pragma unroll
            for (int ib = 0; ib < 2; ++ib) {
                h2 ab = aq[ia] * bq[ib];
                #pragma unroll
                for (int ic = 0; ic < 2; ++ic) {
                    h2 abc = ab * cq[ic];
                    #pragma unroll
                    for (int id = 0; id < 2; ++id)
                        st[ia*8 + ib*4 + ic*2 + id] = abc * dq[id];
                }
            }
        }

        // layer-0 CNOTs (RYs merged): CNOT(0,1), CNOT(2,3), CNOT(1,2)
        #pragma unroll
        for (int s0 = 0; s0 < 16; ++s0)
            if ((s0 & 8) && !(s0 & 4)) { h2 tmp = st[s0]; st[s0] = st[s0|4]; st[s0|4] = tmp; }
        #pragma unroll
        for (int s0 = 0; s0 < 16; ++s0)
            if ((s0 & 2) && !(s0 & 1)) { h2 tmp = st[s0]; st[s0] = st[s0|1]; st[s0|1] = tmp; }
        #pragma unroll
        for (int s0 = 0; s0 < 16; ++s0)
            if ((s0 & 4) && !(s0 & 2)) { h2 tmp = st[s0]; st[s0] = st[s0|2]; st[s0|2] = tmp; }

        // layers 1..3: tan-Givens RY (2 pk-FMA/pair), then the 3 CNOTs
        #pragma unroll
        for (int l = 0; l < 3; ++l) {
            #pragma unroll
            for (int q = 0; q < 4; ++q) {
                h2 tt = tw[l*4 + q];
                const int m = 1 << (3 - q);
                #pragma unroll
                for (int s0 = 0; s0 < 16; ++s0) {
                    if (s0 & m) continue;
                    int s1i = s0 | m;
                    h2 va = st[s0], vb = st[s1i];
                    st[s0]  = va - tt * vb;   // v_pk_fma_f16
                    st[s1i] = tt * va + vb;   // v_pk_fma_f16
                }
            }
            #pragma unroll
            for (int s0 = 0; s0 < 16; ++s0)
                if ((s0 & 8) && !(s0 & 4)) { h2 tmp = st[s0]; st[s0] = st[s0|4]; st[s0|4] = tmp; }
            #pragma unroll
            for (int s0 = 0; s0 < 16; ++s0)
                if ((s0 & 2) && !(s0 & 1)) { h2 tmp = st[s0]; st[s0] = st[s0|1]; st[s0|1] = tmp; }
            #pragma unroll
            for (int s0 = 0; s0 < 16; ++s0)
                if ((s0 & 4) && !(s0 & 2)) { h2 tmp = st[s0]; st[s0] = st[s0|2]; st[s0|2] = tmp; }
        }

        // probabilities + factorized signed sums, packed f16
        h2 p[16];
        #pragma unroll
        for (int s0 = 0; s0 < 16; ++s0) p[s0] = st[s0] * st[s0];

        h2 A0 = (p[0] + p[1]) + (p[2] + p[3]);
        h2 A1 = (p[4] + p[5]) + (p[6] + p[7]);
        h2 A2 = (p[8] + p[9]) + (p[10] + p[11]);
        h2 A3 = (p[12] + p[13]) + (p[14] + p[15]);
        h2 B0 = (p[0] + p[4]) + (p[8] + p[12]);
        h2 B1 = (p[1] + p[5]) + (p[9] + p[13]);
        h2 B2 = (p[2] + p[6]) + (p[10] + p[14]);
        h2 B3 = (p[3] + p[7]) + (p[11] + p[15]);
        h2 zc0 = (A0 + A1) - (A2 + A3);   // sign by bit3
        h2 zc1 = (A0 + A2) - (A1 + A3);   // sign by bit2
        h2 zc2 = (B0 + B1) - (B2 + B3);   // sign by bit1
        h2 zc3 = (B0 + B2) - (B1 + B3);   // sign by bit0

        // accumulate across channels in f32
        z0 += (v2f){(float)zc0.x, (float)zc0.y};
        z1 += (v2f){(float)zc1.x, (float)zc1.y};
        z2 += (v2f){(float)zc2.x, (float)zc2.y};
        z3 += (v2f){(float)zc3.x, (float)zc3.y};
    }

    // fold the uniform tan-Givens scale (weights-only, channel-independent)
    z0 *= sc2; z1 *= sc2; z2 *= sc2; z3 *= sc2;

    // pixel 1 at tid, pixel 2 at tid + 16*127*127
    reinterpret_cast<float4*>(out)[tid]         = make_float4(z0.x, z1.x, z2.x, z3.x);
    reinterpret_cast<float4*>(out)[tid + NHALF] = make_float4(z0.y, z1.y, z2.y, z3.y);
}

extern "C" void kernel_launch(void* const* d_in, const int* in_sizes, int n_in,
                              void* d_out, int out_size, void* d_ws, size_t ws_size,
                              hipStream_t stream) {
    const float* x = (const float*)d_in[0];
    const float* w = (const float*)d_in[1];
    float* out = (float*)d_out;

    const int NHALF = HALFB * RDIM * RDIM;          // 258,064
    int blocks = (NHALF + 255) / 256;               // 1009
    rqcnn_kernel<<<blocks, 256, 0, stream>>>(x, w, out);
}

// Round 10
// 66.695 us; speedup vs baseline: 1.0147x; 1.0147x over previous
//
#include <hip/hip_runtime.h>

// RQCNN quanvolution: B=32, C=3, H=W=128, K=2 -> R=127, 4 qubits, 4 layers.
// Output [B,4,R,R] is a flat reinterpretation of q_out [B,R,R,4].
//
// R10 = revert to R7 (best measured: 67.1 us). R9's packed-f16 body was
// neutral-to-worse (67.7) -> f16 complexity removed. Final structure:
//  - 2 pixels/thread (b, b+16) as float2 ext-vectors (v_pk f32 issue density)
//  - layer-0 RY merged into encoding angles (RY(w)RY(pi x) = RY(pi x + w))
//  - native v_sin/v_cos (revolutions; args tiny -> no range reduction)
//  - tan-Givens: 2 FMA/pair, uniform cos-product folded as one S^2 scale
//  - CNOTs = compile-time register renames (zero instructions)
//  - coalesced float4 stores; kernel ~7us on a ~60us harness floor.

#define BATCH   32
#define CHAN    3
#define HDIM    128
#define WDIM    128
#define RDIM    127
#define HALFB   16

typedef float v2 __attribute__((ext_vector_type(2)));

__global__ __launch_bounds__(256) void rqcnn_kernel(
    const float* __restrict__ x,   // [B,C,H,W]
    const float* __restrict__ w,   // [4,4] weights
    float* __restrict__ out)       // [B*R*R*4]
{
    __shared__ float tw_s[12];     // tan(w/2) for layers 1..3
    __shared__ float wrev_s[4];    // layer-0 weights in revolutions (merged into encoding)
    __shared__ float cw_tmp[16];
    __shared__ float sc2_s;        // (prod cos(w/2), layers 1..3)^2
    const int t = threadIdx.x;
    if (t < 16) {
        float rev = w[t] * 0.07957747154594767f;   // w/(4*pi): half-angle in revolutions
        float c = __builtin_amdgcn_cosf(rev);
        float s = __builtin_amdgcn_sinf(rev);
        cw_tmp[t] = c;
        if (t >= 4) tw_s[t - 4] = s / c;           // precise div, once per block
        else        wrev_s[t]   = rev;
    }
    __syncthreads();
    if (t == 0) {
        float P = 1.f;
        #pragma unroll
        for (int k = 4; k < 16; ++k) P *= cw_tmp[k];
        sc2_s = P * P;
    }
    __syncthreads();

    // hoist to registers (compile-time indices -> VGPRs, one-time LDS read)
    float tw[12];
    #pragma unroll
    for (int k = 0; k < 12; ++k) tw[k] = tw_s[k];
    float wr0 = wrev_s[0], wr1 = wrev_s[1], wr2 = wrev_s[2], wr3 = wrev_s[3];
    float sc2 = sc2_s;

    const int NHALF = HALFB * RDIM * RDIM;     // 258,064 threads, 2 pixels each
    int tid = blockIdx.x * 256 + t;
    if (tid >= NHALF) return;

    int j    = tid % RDIM;
    int rest = tid / RDIM;
    int i    = rest % RDIM;
    int b    = rest / RDIM;                    // 0..15; second pixel is b+16

    const int XOFF = HALFB * CHAN * HDIM * WDIM;   // offset of batch b+16

    v2 z0 = 0.f, z1 = 0.f, z2 = 0.f, z3 = 0.f;

    for (int c = 0; c < CHAN; ++c) {
        int base = ((b * CHAN + c) * HDIM + i) * WDIM + j;
        v2 v0, v1, v2v, v3;
        v0.x  = x[base];              v0.y  = x[base + XOFF];
        v1.x  = x[base + 1];          v1.y  = x[base + XOFF + 1];
        v2v.x = x[base + WDIM];       v2v.y = x[base + XOFF + WDIM];
        v3.x  = x[base + WDIM + 1];   v3.y  = x[base + XOFF + WDIM + 1];

        // merged encoding + layer-0 RY: half-angle (pi*v + w0q)/2 in revolutions
        v2 a0 = 0.25f * v0 + wr0;
        v2 a1 = 0.25f * v1 + wr1;
        v2 a2 = 0.25f * v2v + wr2;
        v2 a3 = 0.25f * v3 + wr3;

        v2 ca0, sa0, ca1, sa1, ca2, sa2, ca3, sa3;
        ca0.x = __builtin_amdgcn_cosf(a0.x); ca0.y = __builtin_amdgcn_cosf(a0.y);
        sa0.x = __builtin_amdgcn_sinf(a0.x); sa0.y = __builtin_amdgcn_sinf(a0.y);
        ca1.x = __builtin_amdgcn_cosf(a1.x); ca1.y = __builtin_amdgcn_cosf(a1.y);
        sa1.x = __builtin_amdgcn_sinf(a1.x); sa1.y = __builtin_amdgcn_sinf(a1.y);
        ca2.x = __builtin_amdgcn_cosf(a2.x); ca2.y = __builtin_amdgcn_cosf(a2.y);
        sa2.x = __builtin_amdgcn_sinf(a2.x); sa2.y = __builtin_amdgcn_sinf(a2.y);
        ca3.x = __builtin_amdgcn_cosf(a3.x); ca3.y = __builtin_amdgcn_cosf(a3.y);
        sa3.x = __builtin_amdgcn_sinf(a3.x); sa3.y = __builtin_amdgcn_sinf(a3.y);

        // qubit q maps to bit (3-q) of flat index s
        v2 aq[2] = {ca0, sa0};
        v2 bq[2] = {ca1, sa1};
        v2 cq[2] = {ca2, sa2};
        v2 dq[2] = {ca3, sa3};

        v2 st[16];
        #pragma unroll
        for (int ia = 0; ia < 2; ++ia) {
            #pragma unroll
            for (int ib = 0; ib < 2; ++ib) {
                v2 ab = aq[ia] * bq[ib];
                #pragma unroll
                for (int ic = 0; ic < 2; ++ic) {
                    v2 abc = ab * cq[ic];
                    #pragma unroll
                    for (int id = 0; id < 2; ++id)
                        st[ia*8 + ib*4 + ic*2 + id] = abc * dq[id];
                }
            }
        }

        // layer-0 CNOTs (RYs merged): CNOT(0,1), CNOT(2,3), CNOT(1,2)
        #pragma unroll
        for (int s0 = 0; s0 < 16; ++s0)
            if ((s0 & 8) && !(s0 & 4)) { v2 tmp = st[s0]; st[s0] = st[s0|4]; st[s0|4] = tmp; }
        #pragma unroll
        for (int s0 = 0; s0 < 16; ++s0)
            if ((s0 & 2) && !(s0 & 1)) { v2 tmp = st[s0]; st[s0] = st[s0|1]; st[s0|1] = tmp; }
        #pragma unroll
        for (int s0 = 0; s0 < 16; ++s0)
            if ((s0 & 4) && !(s0 & 2)) { v2 tmp = st[s0]; st[s0] = st[s0|2]; st[s0|2] = tmp; }

        // layers 1..3: tan-Givens RY (2 FMA/pair), then the 3 CNOTs
        #pragma unroll
        for (int l = 0; l < 3; ++l) {
            #pragma unroll
            for (int q = 0; q < 4; ++q) {
                float tt = tw[l*4 + q];
                const int m = 1 << (3 - q);
                #pragma unroll
                for (int s0 = 0; s0 < 16; ++s0) {
                    if (s0 & m) continue;
                    int s1i = s0 | m;
                    v2 va = st[s0], vb = st[s1i];
                    st[s0]  = va - tt * vb;   // fma
                    st[s1i] = tt * va + vb;   // fma
                }
            }
            #pragma unroll
            for (int s0 = 0; s0 < 16; ++s0)
                if ((s0 & 8) && !(s0 & 4)) { v2 tmp = st[s0]; st[s0] = st[s0|4]; st[s0|4] = tmp; }
            #pragma unroll
            for (int s0 = 0; s0 < 16; ++s0)
                if ((s0 & 2) && !(s0 & 1)) { v2 tmp = st[s0]; st[s0] = st[s0|1]; st[s0|1] = tmp; }
            #pragma unroll
            for (int s0 = 0; s0 < 16; ++s0)
                if ((s0 & 4) && !(s0 & 2)) { v2 tmp = st[s0]; st[s0] = st[s0|2]; st[s0|2] = tmp; }
        }

        // probabilities + factorized signed sums (scale folded in after c-loop)
        v2 p[16];
        #pragma unroll
        for (int s0 = 0; s0 < 16; ++s0) p[s0] = st[s0] * st[s0];

        v2 A0 = (p[0] + p[1]) + (p[2] + p[3]);
        v2 A1 = (p[4] + p[5]) + (p[6] + p[7]);
        v2 A2 = (p[8] + p[9]) + (p[10] + p[11]);
        v2 A3 = (p[12] + p[13]) + (p[14] + p[15]);
        v2 B0 = (p[0] + p[4]) + (p[8] + p[12]);
        v2 B1 = (p[1] + p[5]) + (p[9] + p[13]);
        v2 B2 = (p[2] + p[6]) + (p[10] + p[14]);
        v2 B3 = (p[3] + p[7]) + (p[11] + p[15]);
        z0 += (A0 + A1) - (A2 + A3);   // sign by bit3
        z1 += (A0 + A2) - (A1 + A3);   // sign by bit2
        z2 += (B0 + B1) - (B2 + B3);   // sign by bit1
        z3 += (B0 + B2) - (B1 + B3);   // sign by bit0
    }

    // fold the uniform tan-Givens scale (weights-only, channel-independent)
    z0 *= sc2; z1 *= sc2; z2 *= sc2; z3 *= sc2;

    // pixel 1 at tid, pixel 2 at tid + 16*127*127
    reinterpret_cast<float4*>(out)[tid]         = make_float4(z0.x, z1.x, z2.x, z3.x);
    reinterpret_cast<float4*>(out)[tid + NHALF] = make_float4(z0.y, z1.y, z2.y, z3.y);
}

extern "C" void kernel_launch(void* const* d_in, const int* in_sizes, int n_in,
                              void* d_out, int out_size, void* d_ws, size_t ws_size,
                              hipStream_t stream) {
    const float* x = (const float*)d_in[0];
    const float* w = (const float*)d_in[1];
    float* out = (float*)d_out;

    const int NHALF = HALFB * RDIM * RDIM;          // 258,064
    int blocks = (NHALF + 255) / 256;               // 1009
    rqcnn_kernel<<<blocks, 256, 0, stream>>>(x, w, out);
}